// Round 8
// baseline (684.865 us; speedup 1.0000x reference)
//
#include <hip/hip_runtime.h>

#define N_NODES 100000
#define N_EDGES 1600000
#define F 128

// bucketed CSR build with in-bucket counting sort by src-block
#define BSHIFT 9
#define BNODES 512                       // nodes per bucket
#define NBUCK 196                        // ceil(100000/512)
#define P1_BLOCKS 128
#define P1_TPB 256
#define EPB1 (N_EDGES / P1_BLOCKS)       // 12500 edges per pass-1 block
#define CAPB 160                         // staging capacity per (bucket, block)
#define SRC_SHIFT 12
#define NSPLIT 25
#define KEYS (BNODES * NSPLIT)           // 12800 counters = 50 KB LDS
#define P2_TPB 512

typedef _Float16 f16x8 __attribute__((ext_vector_type(8)));
typedef _Float16 f16x4 __attribute__((ext_vector_type(4)));
typedef _Float16 f16x2 __attribute__((ext_vector_type(2)));
typedef float f32x4 __attribute__((ext_vector_type(4)));

// ---------------- pass 1: partition packed edges into block-private bucket segments ----------------
__global__ __launch_bounds__(P1_TPB) void k_part(const int* __restrict__ src,
                                                 const int* __restrict__ dst,
                                                 int* __restrict__ stage,
                                                 int* __restrict__ pcnt) {
    __shared__ int cnt[NBUCK];
    int t = threadIdx.x, blk = blockIdx.x;
    if (t < NBUCK) cnt[t] = 0;
    __syncthreads();
    int base = blk * EPB1;
    for (int i = t; i < EPB1; i += P1_TPB) {
        int e = base + i;
        int s = src[e], d = dst[e];
        int b = d >> BSHIFT;
        int pos = atomicAdd(&cnt[b], 1);
        if (pos < CAPB)
            stage[((long)b * P1_BLOCKS + blk) * CAPB + pos] = (s << BSHIFT) | (d & (BNODES - 1));
    }
    __syncthreads();
    if (t < NBUCK) pcnt[t * P1_BLOCKS + blk] = min(cnt[t], CAPB);
}

// ---------------- bucket totals -> exclusive bases ----------------
__global__ void k_bucketsum(const int* __restrict__ pcnt, int* __restrict__ bbase,
                            int* __restrict__ row_start) {
    __shared__ int tot[NBUCK];
    int t = threadIdx.x;
    for (int b = t; b < NBUCK; b += 256) {
        int s = 0;
        for (int i = 0; i < P1_BLOCKS; i++) s += pcnt[b * P1_BLOCKS + i];
        tot[b] = s;
    }
    __syncthreads();
    if (t == 0) {
        int acc = 0;
        for (int i = 0; i < NBUCK; i++) {
            bbase[i] = acc;
            acc += tot[i];
        }
        bbase[NBUCK] = acc;
        row_start[N_NODES] = acc;
    }
}

// ---------------- pass 2: per-bucket counting sort on (local_dst, src_block) ----------------
__global__ __launch_bounds__(P2_TPB) void k_build(const int* __restrict__ stage,
                                                  const int* __restrict__ pcnt,
                                                  const int* __restrict__ bbase,
                                                  int* __restrict__ row_start,
                                                  int* __restrict__ esrc) {
    __shared__ int cnt[KEYS];
    __shared__ int scanw[P2_TPB / 64];
    int b = blockIdx.x, t = threadIdx.x;
    int nodeBase = b * BNODES;
    for (int i = t; i < KEYS; i += P2_TPB) cnt[i] = 0;
    __syncthreads();
    int grp = t >> 7, gt = t & 127;
    for (int s = grp; s < P1_BLOCKS; s += 4) {
        int n = pcnt[b * P1_BLOCKS + s];
        const int* seg = &stage[((long)b * P1_BLOCKS + s) * CAPB];
        for (int i = gt; i < n; i += 128) {
            int pk = seg[i];
            atomicAdd(&cnt[(pk & (BNODES - 1)) * NSPLIT + (pk >> (BSHIFT + SRC_SHIFT))], 1);
        }
    }
    __syncthreads();
    int kbase = t * 25;
    int sum = 0;
#pragma unroll
    for (int i = 0; i < 25; i++) sum += cnt[kbase + i];
    int lane = t & 63, wv = t >> 6;
    int x = sum;
#pragma unroll
    for (int off = 1; off < 64; off <<= 1) {
        int y = __shfl_up(x, off, 64);
        if (lane >= off) x += y;
    }
    if (lane == 63) scanw[wv] = x;
    __syncthreads();
    if (t == 0) {
        int acc = 0;
        for (int i = 0; i < P2_TPB / 64; i++) {
            int y = scanw[i];
            scanw[i] = acc;
            acc += y;
        }
    }
    __syncthreads();
    int run = x - sum + scanw[wv];
#pragma unroll
    for (int i = 0; i < 25; i++) {
        int c = cnt[kbase + i];
        cnt[kbase + i] = run;
        run += c;
    }
    __syncthreads();
    int base0 = bbase[b];
    {
        int node = nodeBase + t;
        if (t < BNODES && node < N_NODES) row_start[node] = base0 + cnt[t * NSPLIT];
    }
    __syncthreads();
    for (int s = grp; s < P1_BLOCKS; s += 4) {
        int n = pcnt[b * P1_BLOCKS + s];
        const int* seg = &stage[((long)b * P1_BLOCKS + s) * CAPB];
        for (int i = gt; i < n; i += 128) {
            int pk = seg[i];
            int pos = atomicAdd(&cnt[(pk & (BNODES - 1)) * NSPLIT + (pk >> (BSHIFT + SRC_SHIFT))], 1);
            esrc[base0 + pos] = pk >> BSHIFT;
        }
    }
}

// ---------------- cast x -> chunk-major fp16: xc[c][node][16] ----------------
__global__ void k_cast(const float* __restrict__ x, _Float16* __restrict__ xc) {
    int i = blockIdx.x * blockDim.x + threadIdx.x;  // 800000 threads
    int node = i >> 3, c = i & 7;
    const float* xp = &x[(long)node * F + c * 16];
    _Float16 h[16];
#pragma unroll
    for (int j = 0; j < 16; j++) h[j] = (_Float16)xp[j];
    _Float16* op = &xc[((long)c * N_NODES + node) * 16];
    *(f16x8*)op = *(f16x8*)&h[0];
    *(f16x8*)(op + 8) = *(f16x8*)&h[8];
}

// Wt[n][k] fp16 for both layers in one launch
__global__ void k_prepw(const float* __restrict__ Ws1, const float* __restrict__ Wn1,
                        const float* __restrict__ Ws2, const float* __restrict__ Wn2,
                        _Float16* __restrict__ Wt1, _Float16* __restrict__ Wt2) {
    int i = blockIdx.x * blockDim.x + threadIdx.x;
    int which = i >> 15;
    int j = i & 32767;
    int n = j >> 8;
    int k = j & 255;
    const float* Ws = which ? Ws2 : Ws1;
    const float* Wn = which ? Wn2 : Wn1;
    _Float16* Wt = which ? Wt2 : Wt1;
    float v = (k < 128) ? Ws[k * F + n] : Wn[(k - 128) * F + n];
    Wt[n * 256 + k] = (_Float16)v;
}

// ---------------- aggregation: chunk-plane (XCD-L2-resident) + register edge list ----------------
// One wave per (node, chunk). chunk = blockIdx&7 -> round-robin pins plane to one XCD.
// Lanes hold the edge list; 8 groups x 8 lanes gather 8 edge-rows (32 B each) per instr.
__global__ __launch_bounds__(256) void k_agg(const f16x2* __restrict__ xc,
                                             const int* __restrict__ row_start,
                                             const int* __restrict__ esrc,
                                             f16x2* __restrict__ outc) {
    int c = blockIdx.x & 7;
    int nb = blockIdx.x >> 3;                 // 0..24999
    int w = threadIdx.x >> 6;
    int lane = threadIdx.x & 63;
    int node = nb * 4 + w;                    // 25000*4 == 100000 exact
    int grp = lane >> 3;                      // edge subgroup 0..7
    int col = lane & 7;                       // f16x2 within 32 B row
    int beg = row_start[node], end = row_start[node + 1];
    int deg = end - beg;
    int n64 = min(deg, 64);
    int e = 0;
    if (lane < n64) e = __builtin_nontemporal_load(&esrc[beg + lane]);
    const f16x2* plane = xc + (long)c * (N_NODES * 8);
    float ax = 0.f, ay = 0.f;
    for (int i = 0; i < n64; i += 16) {
        int i0 = i + grp, i1 = i + 8 + grp;
        int s0 = __shfl(e, i0, 64);
        int s1 = __shfl(e, i1, 64);
        f16x2 v0 = plane[(long)s0 * 8 + col];
        f16x2 v1 = plane[(long)s1 * 8 + col];
        if (i0 < n64) { ax += (float)v0.x; ay += (float)v0.y; }
        if (i1 < n64) { ax += (float)v1.x; ay += (float)v1.y; }
    }
    // rare tail: deg > 64 (groups split the remainder)
    for (int j = beg + 64 + grp; j < end; j += 8) {
        int s = __builtin_nontemporal_load(&esrc[j]);
        f16x2 v = plane[(long)s * 8 + col];
        ax += (float)v.x;
        ay += (float)v.y;
    }
    ax += __shfl_xor(ax, 8, 64);
    ay += __shfl_xor(ay, 8, 64);
    ax += __shfl_xor(ax, 16, 64);
    ay += __shfl_xor(ay, 16, 64);
    ax += __shfl_xor(ax, 32, 64);
    ay += __shfl_xor(ay, 32, 64);
    if (grp == 0) {
        float inv = (deg > 0) ? 1.0f / (float)deg : 0.0f;
        f16x2 r;
        r.x = (_Float16)(ax * inv);
        r.y = (_Float16)(ay * inv);
        __builtin_nontemporal_store(r, &outc[(long)c * (N_NODES * 8) + (long)node * 8 + col]);
    }
}

// ---------------- MFMA GEMM (A chunk-major, B staged in LDS fragment-order) ----------------
template <bool FINAL>
__global__ __launch_bounds__(256, 2) void k_gemm_mfma(
    const _Float16* __restrict__ Aself, const _Float16* __restrict__ Aneigh,
    const _Float16* __restrict__ Wt, const float* __restrict__ bias,
    _Float16* __restrict__ Hout, const float* __restrict__ Wf,
    const float* __restrict__ bf, float* __restrict__ Out) {
    const int M = N_NODES;
    __shared__ _Float16 Wl[4096 * 8];  // 64 KB
    int w = threadIdx.x >> 6;
    int lane = threadIdx.x & 63;
    int q = lane >> 4;
    int ln = lane & 15;
    int rBase = blockIdx.x * 128 + w * 32;

#pragma unroll
    for (int i = 0; i < 16; i++) {
        int s = threadIdx.x + i * 256;
        int L = s & 63, ct = (s >> 6) & 7, ks = s >> 9;
        int g = (ct * 16 + (L & 15)) * 256 + ks * 32 + (L >> 4) * 8;
        *(f16x8*)&Wl[s * 8] = *(const f16x8*)&Wt[g];
    }

    f32x4 acc[2][8];
#pragma unroll
    for (int rt = 0; rt < 2; rt++)
#pragma unroll
        for (int ct = 0; ct < 8; ct++) acc[rt][ct] = (f32x4){0.f, 0.f, 0.f, 0.f};

    __syncthreads();

    for (int ks = 0; ks < 8; ks++) {
        const _Float16* Abase = (ks < 4) ? Aself : Aneigh;
        int kk = (ks & 3) * 32 + q * 8;
        int chk = kk >> 4;
        int inner = kk & 15;
        f16x8 b[8];
#pragma unroll
        for (int ct = 0; ct < 8; ct++)
            b[ct] = *(const f16x8*)&Wl[((ks * 8 + ct) * 64 + lane) * 8];
#pragma unroll
        for (int rt = 0; rt < 2; rt++) {
            int row = rBase + rt * 16 + ln;
            f16x8 a = {};
            if (row < M) a = *(const f16x8*)&Abase[((long)chk * N_NODES + row) * 16 + inner];
#pragma unroll
            for (int ct = 0; ct < 8; ct++)
                acc[rt][ct] = __builtin_amdgcn_mfma_f32_16x16x32_f16(a, b[ct], acc[rt][ct], 0, 0, 0);
        }
    }

    float bv[8];
#pragma unroll
    for (int ct = 0; ct < 8; ct++) bv[ct] = bias[ct * 16 + ln];

    if (!FINAL) {
#pragma unroll
        for (int rt = 0; rt < 2; rt++) {
#pragma unroll
            for (int r = 0; r < 4; r++) {
                int row = rBase + rt * 16 + q * 4 + r;
                if (row < M) {
#pragma unroll
                    for (int ct = 0; ct < 8; ct++) {
                        float h = acc[rt][ct][r] + bv[ct];
                        h = h > 0.f ? h : 0.f;
                        Hout[((long)ct * N_NODES + row) * 16 + ln] = (_Float16)h;
                    }
                }
            }
        }
    } else {
        float wf0[8], wf1[8];
#pragma unroll
        for (int ct = 0; ct < 8; ct++) {
            int c = ct * 16 + ln;
            wf0[ct] = Wf[c * 2 + 0];
            wf1[ct] = Wf[c * 2 + 1];
        }
        float bf0 = bf[0], bf1 = bf[1];
#pragma unroll
        for (int rt = 0; rt < 2; rt++) {
#pragma unroll
            for (int r = 0; r < 4; r++) {
                int row = rBase + rt * 16 + q * 4 + r;
                float p0 = 0.f, p1 = 0.f;
#pragma unroll
                for (int ct = 0; ct < 8; ct++) {
                    float h = acc[rt][ct][r] + bv[ct];
                    h = h > 0.f ? h : 0.f;
                    p0 += h * wf0[ct];
                    p1 += h * wf1[ct];
                }
#pragma unroll
                for (int off = 1; off < 16; off <<= 1) {
                    p0 += __shfl_xor(p0, off, 64);
                    p1 += __shfl_xor(p1, off, 64);
                }
                if (ln == 0 && row < M) {
                    Out[(long)row * 2 + 0] = p0 + bf0;
                    Out[(long)row * 2 + 1] = p1 + bf1;
                }
            }
        }
    }
}

// ---------------- launch ----------------
extern "C" void kernel_launch(void* const* d_in, const int* in_sizes, int n_in,
                              void* d_out, int out_size, void* d_ws, size_t ws_size,
                              hipStream_t stream) {
    const float* x   = (const float*)d_in[0];
    const float* Ws1 = (const float*)d_in[1];
    const float* Wn1 = (const float*)d_in[2];
    const float* b1  = (const float*)d_in[3];
    const float* Ws2 = (const float*)d_in[4];
    const float* Wn2 = (const float*)d_in[5];
    const float* b2  = (const float*)d_in[6];
    const float* Wf  = (const float*)d_in[7];
    const float* bf  = (const float*)d_in[8];
    const int* src   = (const int*)d_in[9];
    const int* dst   = (const int*)d_in[10];
    float* out = (float*)d_out;

    char* ws = (char*)d_ws;
    int*      row_start = (int*)(ws + 0);               // 400,016
    int*      bbase     = (int*)(ws + 400016);          // 800
    int*      pcnt      = (int*)(ws + 400816);          // 100,352
    int*      stage     = (int*)(ws + 501184);          // 16,056,320
    int*      esrc      = (int*)(ws + 16557504);        // 6,400,000
    _Float16* xh        = (_Float16*)(ws + 22957504);   // 25,600,000 (chunk-major)
    _Float16* hneigh    = (_Float16*)(ws + 48557504);   // 25,600,000 (chunk-major)
    _Float16* h1        = (_Float16*)(ws + 74157504);   // 25,600,000 (chunk-major)
    _Float16* Wt1       = (_Float16*)(ws + 99757504);   // 65,536
    _Float16* Wt2       = (_Float16*)(ws + 99823040);   // 65,536

    // CSR build (src-sorted rows, single-pass counting sort)
    k_part<<<P1_BLOCKS, P1_TPB, 0, stream>>>(src, dst, stage, pcnt);
    k_bucketsum<<<1, 256, 0, stream>>>(pcnt, bbase, row_start);
    k_build<<<NBUCK, P2_TPB, 0, stream>>>(stage, pcnt, bbase, row_start, esrc);

    // dtype prep
    k_cast<<<3125, 256, 0, stream>>>(x, xh);
    k_prepw<<<256, 256, 0, stream>>>(Ws1, Wn1, Ws2, Wn2, Wt1, Wt2);

    // layer 1
    k_agg<<<200000, 256, 0, stream>>>((const f16x2*)xh, row_start, esrc, (f16x2*)hneigh);
    k_gemm_mfma<false><<<(N_NODES + 127) / 128, 256, 0, stream>>>(
        xh, hneigh, Wt1, b1, h1, nullptr, nullptr, nullptr);
    // layer 2 + fused final projection
    k_agg<<<200000, 256, 0, stream>>>((const f16x2*)h1, row_start, esrc, (f16x2*)hneigh);
    k_gemm_mfma<true><<<(N_NODES + 127) / 128, 256, 0, stream>>>(
        h1, hneigh, Wt2, b2, nullptr, Wf, bf, out);
}

// Round 9
// 683.129 us; speedup vs baseline: 1.0025x; 1.0025x over previous
//
#include <hip/hip_runtime.h>

#define N_NODES 100000
#define N_EDGES 1600000
#define F 128

// bucketed CSR build with in-bucket counting sort by src-block
#define BSHIFT 9
#define BNODES 512                       // nodes per bucket
#define NBUCK 196                        // ceil(100000/512)
#define P1_BLOCKS 128
#define P1_TPB 256
#define EPB1 (N_EDGES / P1_BLOCKS)       // 12500 edges per pass-1 block
#define CAPB 160                         // staging capacity per (bucket, block)
#define SRC_SHIFT 12
#define NSPLIT 25
#define KEYS (BNODES * NSPLIT)           // 12800 counters = 50 KB LDS
#define P2_TPB 512

typedef _Float16 f16x8 __attribute__((ext_vector_type(8)));
typedef _Float16 f16x4 __attribute__((ext_vector_type(4)));
typedef _Float16 f16x2 __attribute__((ext_vector_type(2)));
typedef float f32x4 __attribute__((ext_vector_type(4)));

// ---------------- pass 1: partition packed edges into block-private bucket segments ----------------
__global__ __launch_bounds__(P1_TPB) void k_part(const int* __restrict__ src,
                                                 const int* __restrict__ dst,
                                                 int* __restrict__ stage,
                                                 int* __restrict__ pcnt) {
    __shared__ int cnt[NBUCK];
    int t = threadIdx.x, blk = blockIdx.x;
    if (t < NBUCK) cnt[t] = 0;
    __syncthreads();
    int base = blk * EPB1;
    for (int i = t; i < EPB1; i += P1_TPB) {
        int e = base + i;
        int s = src[e], d = dst[e];
        int b = d >> BSHIFT;
        int pos = atomicAdd(&cnt[b], 1);
        if (pos < CAPB)
            stage[((long)b * P1_BLOCKS + blk) * CAPB + pos] = (s << BSHIFT) | (d & (BNODES - 1));
    }
    __syncthreads();
    if (t < NBUCK) pcnt[t * P1_BLOCKS + blk] = min(cnt[t], CAPB);
}

// ---------------- bucket totals -> exclusive bases ----------------
__global__ void k_bucketsum(const int* __restrict__ pcnt, int* __restrict__ bbase,
                            int* __restrict__ row_start) {
    __shared__ int tot[NBUCK];
    int t = threadIdx.x;
    for (int b = t; b < NBUCK; b += 256) {
        int s = 0;
        for (int i = 0; i < P1_BLOCKS; i++) s += pcnt[b * P1_BLOCKS + i];
        tot[b] = s;
    }
    __syncthreads();
    if (t == 0) {
        int acc = 0;
        for (int i = 0; i < NBUCK; i++) {
            bbase[i] = acc;
            acc += tot[i];
        }
        bbase[NBUCK] = acc;
        row_start[N_NODES] = acc;
    }
}

// ---------------- pass 2: per-bucket counting sort on (local_dst, src_block) ----------------
__global__ __launch_bounds__(P2_TPB) void k_build(const int* __restrict__ stage,
                                                  const int* __restrict__ pcnt,
                                                  const int* __restrict__ bbase,
                                                  int* __restrict__ row_start,
                                                  int* __restrict__ esrc) {
    __shared__ int cnt[KEYS];
    __shared__ int scanw[P2_TPB / 64];
    int b = blockIdx.x, t = threadIdx.x;
    int nodeBase = b * BNODES;
    for (int i = t; i < KEYS; i += P2_TPB) cnt[i] = 0;
    __syncthreads();
    int grp = t >> 7, gt = t & 127;
    for (int s = grp; s < P1_BLOCKS; s += 4) {
        int n = pcnt[b * P1_BLOCKS + s];
        const int* seg = &stage[((long)b * P1_BLOCKS + s) * CAPB];
        for (int i = gt; i < n; i += 128) {
            int pk = seg[i];
            atomicAdd(&cnt[(pk & (BNODES - 1)) * NSPLIT + (pk >> (BSHIFT + SRC_SHIFT))], 1);
        }
    }
    __syncthreads();
    int kbase = t * 25;
    int sum = 0;
#pragma unroll
    for (int i = 0; i < 25; i++) sum += cnt[kbase + i];
    int lane = t & 63, wv = t >> 6;
    int x = sum;
#pragma unroll
    for (int off = 1; off < 64; off <<= 1) {
        int y = __shfl_up(x, off, 64);
        if (lane >= off) x += y;
    }
    if (lane == 63) scanw[wv] = x;
    __syncthreads();
    if (t == 0) {
        int acc = 0;
        for (int i = 0; i < P2_TPB / 64; i++) {
            int y = scanw[i];
            scanw[i] = acc;
            acc += y;
        }
    }
    __syncthreads();
    int run = x - sum + scanw[wv];
#pragma unroll
    for (int i = 0; i < 25; i++) {
        int c = cnt[kbase + i];
        cnt[kbase + i] = run;
        run += c;
    }
    __syncthreads();
    int base0 = bbase[b];
    {
        int node = nodeBase + t;
        if (t < BNODES && node < N_NODES) row_start[node] = base0 + cnt[t * NSPLIT];
    }
    __syncthreads();
    for (int s = grp; s < P1_BLOCKS; s += 4) {
        int n = pcnt[b * P1_BLOCKS + s];
        const int* seg = &stage[((long)b * P1_BLOCKS + s) * CAPB];
        for (int i = gt; i < n; i += 128) {
            int pk = seg[i];
            int pos = atomicAdd(&cnt[(pk & (BNODES - 1)) * NSPLIT + (pk >> (BSHIFT + SRC_SHIFT))], 1);
            esrc[base0 + pos] = pk >> BSHIFT;
        }
    }
}

// ---------------- cast x -> chunk-major fp16: xc[c][node][16] ----------------
__global__ void k_cast(const float* __restrict__ x, _Float16* __restrict__ xc) {
    int i = blockIdx.x * blockDim.x + threadIdx.x;  // 800000 threads
    int node = i >> 3, c = i & 7;
    const float* xp = &x[(long)node * F + c * 16];
    _Float16 h[16];
#pragma unroll
    for (int j = 0; j < 16; j++) h[j] = (_Float16)xp[j];
    _Float16* op = &xc[((long)c * N_NODES + node) * 16];
    *(f16x8*)op = *(f16x8*)&h[0];
    *(f16x8*)(op + 8) = *(f16x8*)&h[8];
}

// Wt[n][k] fp16 for both layers in one launch
__global__ void k_prepw(const float* __restrict__ Ws1, const float* __restrict__ Wn1,
                        const float* __restrict__ Ws2, const float* __restrict__ Wn2,
                        _Float16* __restrict__ Wt1, _Float16* __restrict__ Wt2) {
    int i = blockIdx.x * blockDim.x + threadIdx.x;
    int which = i >> 15;
    int j = i & 32767;
    int n = j >> 8;
    int k = j & 255;
    const float* Ws = which ? Ws2 : Ws1;
    const float* Wn = which ? Wn2 : Wn1;
    _Float16* Wt = which ? Wt2 : Wt1;
    float v = (k < 128) ? Ws[k * F + n] : Wn[(k - 128) * F + n];
    Wt[n * 256 + k] = (_Float16)v;
}

// ---------------- aggregation: chunk-plane (XCD-L2-pinned) + positional quad gather ----------------
// One wave per (node, chunk); chunk = blockIdx&7 pins each 3.2 MB plane to one XCD's L2.
// lane = (edge slot lane>>2, col lane&3): quad reads one esrc dword (HW broadcast),
// gathers 8 B of the 32 B row; pk_f16 accumulate; shfl_xor tree reduce. No bpermute.
__global__ __launch_bounds__(256) void k_agg(const _Float16* __restrict__ xc,
                                             const int* __restrict__ row_start,
                                             const int* __restrict__ esrc,
                                             _Float16* __restrict__ outc) {
    int c = blockIdx.x & 7;
    int nb = blockIdx.x >> 3;                 // 0..24999
    int w = threadIdx.x >> 6;
    int lane = threadIdx.x & 63;
    int node = nb * 4 + w;                    // 25000*4 == 100000 exact
    int eidx = lane >> 2;                     // edge slot 0..15
    int col4 = lane & 3;                      // f16x4 within 32 B row
    int beg = row_start[node], end = row_start[node + 1];
    int deg = end - beg;
    const _Float16* plane = xc + (long)c * (N_NODES * 16);
    f16x2 a0 = (f16x2){(_Float16)0.f, (_Float16)0.f};
    f16x2 a1 = a0;
    for (int i = 0; i < deg; i += 16) {
        int idx = i + eidx;
        bool valid = idx < deg;
        // may read up to 15 ints past row end: esrc has live data / adjacent ws after it,
        // and e is masked to 0 below, so the gather address stays in-bounds.
        int e = __builtin_nontemporal_load(&esrc[beg + idx]);
        e = valid ? e : 0;
        const f16x2* rp = (const f16x2*)&plane[(long)e * 16 + col4 * 4];
        f16x2 v0 = rp[0];
        f16x2 v1 = rp[1];
        if (valid) {
            a0 += v0;
            a1 += v1;
        }
    }
    // reduce across the 16 edge slots (lanes with equal col4)
#pragma unroll
    for (int off = 4; off <= 32; off <<= 1) {
        int t0 = __shfl_xor(*(int*)&a0, off, 64);
        int t1 = __shfl_xor(*(int*)&a1, off, 64);
        a0 += *(f16x2*)&t0;
        a1 += *(f16x2*)&t1;
    }
    if (eidx == 0) {
        float invf = (deg > 0) ? 1.0f / (float)deg : 0.0f;
        _Float16 ih = (_Float16)invf;
        f16x2 iv = (f16x2){ih, ih};
        a0 *= iv;
        a1 *= iv;
        _Float16* op = &outc[((long)c * N_NODES + node) * 16 + col4 * 4];
        __builtin_nontemporal_store(*(int*)&a0, (int*)op);
        __builtin_nontemporal_store(*(int*)&a1, (int*)(op + 2));
    }
}

// ---------------- MFMA GEMM (A chunk-major, B staged in LDS fragment-order) ----------------
template <bool FINAL>
__global__ __launch_bounds__(256, 2) void k_gemm_mfma(
    const _Float16* __restrict__ Aself, const _Float16* __restrict__ Aneigh,
    const _Float16* __restrict__ Wt, const float* __restrict__ bias,
    _Float16* __restrict__ Hout, const float* __restrict__ Wf,
    const float* __restrict__ bf, float* __restrict__ Out) {
    const int M = N_NODES;
    __shared__ _Float16 Wl[4096 * 8];  // 64 KB
    int w = threadIdx.x >> 6;
    int lane = threadIdx.x & 63;
    int q = lane >> 4;
    int ln = lane & 15;
    int rBase = blockIdx.x * 128 + w * 32;

#pragma unroll
    for (int i = 0; i < 16; i++) {
        int s = threadIdx.x + i * 256;
        int L = s & 63, ct = (s >> 6) & 7, ks = s >> 9;
        int g = (ct * 16 + (L & 15)) * 256 + ks * 32 + (L >> 4) * 8;
        *(f16x8*)&Wl[s * 8] = *(const f16x8*)&Wt[g];
    }

    f32x4 acc[2][8];
#pragma unroll
    for (int rt = 0; rt < 2; rt++)
#pragma unroll
        for (int ct = 0; ct < 8; ct++) acc[rt][ct] = (f32x4){0.f, 0.f, 0.f, 0.f};

    __syncthreads();

    for (int ks = 0; ks < 8; ks++) {
        const _Float16* Abase = (ks < 4) ? Aself : Aneigh;
        int kk = (ks & 3) * 32 + q * 8;
        int chk = kk >> 4;
        int inner = kk & 15;
        f16x8 b[8];
#pragma unroll
        for (int ct = 0; ct < 8; ct++)
            b[ct] = *(const f16x8*)&Wl[((ks * 8 + ct) * 64 + lane) * 8];
#pragma unroll
        for (int rt = 0; rt < 2; rt++) {
            int row = rBase + rt * 16 + ln;
            f16x8 a = {};
            if (row < M) a = *(const f16x8*)&Abase[((long)chk * N_NODES + row) * 16 + inner];
#pragma unroll
            for (int ct = 0; ct < 8; ct++)
                acc[rt][ct] = __builtin_amdgcn_mfma_f32_16x16x32_f16(a, b[ct], acc[rt][ct], 0, 0, 0);
        }
    }

    float bv[8];
#pragma unroll
    for (int ct = 0; ct < 8; ct++) bv[ct] = bias[ct * 16 + ln];

    if (!FINAL) {
#pragma unroll
        for (int rt = 0; rt < 2; rt++) {
#pragma unroll
            for (int r = 0; r < 4; r++) {
                int row = rBase + rt * 16 + q * 4 + r;
                if (row < M) {
#pragma unroll
                    for (int ct = 0; ct < 8; ct++) {
                        float h = acc[rt][ct][r] + bv[ct];
                        h = h > 0.f ? h : 0.f;
                        Hout[((long)ct * N_NODES + row) * 16 + ln] = (_Float16)h;
                    }
                }
            }
        }
    } else {
        float wf0[8], wf1[8];
#pragma unroll
        for (int ct = 0; ct < 8; ct++) {
            int c = ct * 16 + ln;
            wf0[ct] = Wf[c * 2 + 0];
            wf1[ct] = Wf[c * 2 + 1];
        }
        float bf0 = bf[0], bf1 = bf[1];
#pragma unroll
        for (int rt = 0; rt < 2; rt++) {
#pragma unroll
            for (int r = 0; r < 4; r++) {
                int row = rBase + rt * 16 + q * 4 + r;
                float p0 = 0.f, p1 = 0.f;
#pragma unroll
                for (int ct = 0; ct < 8; ct++) {
                    float h = acc[rt][ct][r] + bv[ct];
                    h = h > 0.f ? h : 0.f;
                    p0 += h * wf0[ct];
                    p1 += h * wf1[ct];
                }
#pragma unroll
                for (int off = 1; off < 16; off <<= 1) {
                    p0 += __shfl_xor(p0, off, 64);
                    p1 += __shfl_xor(p1, off, 64);
                }
                if (ln == 0 && row < M) {
                    Out[(long)row * 2 + 0] = p0 + bf0;
                    Out[(long)row * 2 + 1] = p1 + bf1;
                }
            }
        }
    }
}

// ---------------- launch ----------------
extern "C" void kernel_launch(void* const* d_in, const int* in_sizes, int n_in,
                              void* d_out, int out_size, void* d_ws, size_t ws_size,
                              hipStream_t stream) {
    const float* x   = (const float*)d_in[0];
    const float* Ws1 = (const float*)d_in[1];
    const float* Wn1 = (const float*)d_in[2];
    const float* b1  = (const float*)d_in[3];
    const float* Ws2 = (const float*)d_in[4];
    const float* Wn2 = (const float*)d_in[5];
    const float* b2  = (const float*)d_in[6];
    const float* Wf  = (const float*)d_in[7];
    const float* bf  = (const float*)d_in[8];
    const int* src   = (const int*)d_in[9];
    const int* dst   = (const int*)d_in[10];
    float* out = (float*)d_out;

    char* ws = (char*)d_ws;
    int*      row_start = (int*)(ws + 0);               // 400,016
    int*      bbase     = (int*)(ws + 400016);          // 800
    int*      pcnt      = (int*)(ws + 400816);          // 100,352
    int*      stage     = (int*)(ws + 501184);          // 16,056,320
    int*      esrc      = (int*)(ws + 16557504);        // 6,400,000 (+64 B over-read slack into xh)
    _Float16* xh        = (_Float16*)(ws + 22957504);   // 25,600,000 (chunk-major)
    _Float16* hneigh    = (_Float16*)(ws + 48557504);   // 25,600,000 (chunk-major)
    _Float16* h1        = (_Float16*)(ws + 74157504);   // 25,600,000 (chunk-major)
    _Float16* Wt1       = (_Float16*)(ws + 99757504);   // 65,536
    _Float16* Wt2       = (_Float16*)(ws + 99823040);   // 65,536

    // CSR build (src-sorted rows, single-pass counting sort)
    k_part<<<P1_BLOCKS, P1_TPB, 0, stream>>>(src, dst, stage, pcnt);
    k_bucketsum<<<1, 256, 0, stream>>>(pcnt, bbase, row_start);
    k_build<<<NBUCK, P2_TPB, 0, stream>>>(stage, pcnt, bbase, row_start, esrc);

    // dtype prep
    k_cast<<<3125, 256, 0, stream>>>(x, xh);
    k_prepw<<<256, 256, 0, stream>>>(Ws1, Wn1, Ws2, Wn2, Wt1, Wt2);

    // layer 1
    k_agg<<<200000, 256, 0, stream>>>(xh, row_start, esrc, hneigh);
    k_gemm_mfma<false><<<(N_NODES + 127) / 128, 256, 0, stream>>>(
        xh, hneigh, Wt1, b1, h1, nullptr, nullptr, nullptr);
    // layer 2 + fused final projection
    k_agg<<<200000, 256, 0, stream>>>(h1, row_start, esrc, hneigh);
    k_gemm_mfma<true><<<(N_NODES + 127) / 128, 256, 0, stream>>>(
        h1, hneigh, Wt2, b2, nullptr, Wf, bf, out);
}

// Round 12
// 657.587 us; speedup vs baseline: 1.0415x; 1.0388x over previous
//
#include <hip/hip_runtime.h>

#define N_NODES 100000
#define N_EDGES 1600000
#define F 128

// bucketed CSR build with in-bucket counting sort by src-block
#define BSHIFT 9
#define BNODES 512                       // nodes per bucket
#define NBUCK 196                        // ceil(100000/512)
#define P1_BLOCKS 128
#define P1_TPB 256
#define EPB1 (N_EDGES / P1_BLOCKS)       // 12500 edges per pass-1 block
#define CAPB 160                         // staging capacity per (bucket, block)
#define SRC_SHIFT 12
#define NSPLIT 25
#define KEYS (BNODES * NSPLIT)           // 12800 counters = 50 KB LDS
#define P2_TPB 512

typedef _Float16 f16x8 __attribute__((ext_vector_type(8)));
typedef _Float16 f16x4 __attribute__((ext_vector_type(4)));
typedef _Float16 f16x2 __attribute__((ext_vector_type(2)));
typedef float f32x4 __attribute__((ext_vector_type(4)));

// ---------------- pass 1: partition packed edges into block-private bucket segments ----------------
__global__ __launch_bounds__(P1_TPB) void k_part(const int* __restrict__ src,
                                                 const int* __restrict__ dst,
                                                 int* __restrict__ stage,
                                                 int* __restrict__ pcnt) {
    __shared__ int cnt[NBUCK];
    int t = threadIdx.x, blk = blockIdx.x;
    if (t < NBUCK) cnt[t] = 0;
    __syncthreads();
    int base = blk * EPB1;
    for (int i = t; i < EPB1; i += P1_TPB) {
        int e = base + i;
        int s = src[e], d = dst[e];
        int b = d >> BSHIFT;
        int pos = atomicAdd(&cnt[b], 1);
        if (pos < CAPB)
            stage[((long)b * P1_BLOCKS + blk) * CAPB + pos] = (s << BSHIFT) | (d & (BNODES - 1));
    }
    __syncthreads();
    if (t < NBUCK) pcnt[t * P1_BLOCKS + blk] = min(cnt[t], CAPB);
}

// ---------------- bucket totals -> exclusive bases ----------------
__global__ void k_bucketsum(const int* __restrict__ pcnt, int* __restrict__ bbase,
                            int* __restrict__ row_start) {
    __shared__ int tot[NBUCK];
    int t = threadIdx.x;
    for (int b = t; b < NBUCK; b += 256) {
        int s = 0;
        for (int i = 0; i < P1_BLOCKS; i++) s += pcnt[b * P1_BLOCKS + i];
        tot[b] = s;
    }
    __syncthreads();
    if (t == 0) {
        int acc = 0;
        for (int i = 0; i < NBUCK; i++) {
            bbase[i] = acc;
            acc += tot[i];
        }
        bbase[NBUCK] = acc;
        row_start[N_NODES] = acc;
    }
}

// ---------------- pass 2: per-bucket counting sort on (local_dst, src_block) ----------------
__global__ __launch_bounds__(P2_TPB) void k_build(const int* __restrict__ stage,
                                                  const int* __restrict__ pcnt,
                                                  const int* __restrict__ bbase,
                                                  int* __restrict__ row_start,
                                                  int* __restrict__ esrc) {
    __shared__ int cnt[KEYS];
    __shared__ int scanw[P2_TPB / 64];
    int b = blockIdx.x, t = threadIdx.x;
    int nodeBase = b * BNODES;
    for (int i = t; i < KEYS; i += P2_TPB) cnt[i] = 0;
    __syncthreads();
    int grp = t >> 7, gt = t & 127;
    for (int s = grp; s < P1_BLOCKS; s += 4) {
        int n = pcnt[b * P1_BLOCKS + s];
        const int* seg = &stage[((long)b * P1_BLOCKS + s) * CAPB];
        for (int i = gt; i < n; i += 128) {
            int pk = seg[i];
            atomicAdd(&cnt[(pk & (BNODES - 1)) * NSPLIT + (pk >> (BSHIFT + SRC_SHIFT))], 1);
        }
    }
    __syncthreads();
    int kbase = t * 25;
    int sum = 0;
#pragma unroll
    for (int i = 0; i < 25; i++) sum += cnt[kbase + i];
    int lane = t & 63, wv = t >> 6;
    int x = sum;
#pragma unroll
    for (int off = 1; off < 64; off <<= 1) {
        int y = __shfl_up(x, off, 64);
        if (lane >= off) x += y;
    }
    if (lane == 63) scanw[wv] = x;
    __syncthreads();
    if (t == 0) {
        int acc = 0;
        for (int i = 0; i < P2_TPB / 64; i++) {
            int y = scanw[i];
            scanw[i] = acc;
            acc += y;
        }
    }
    __syncthreads();
    int run = x - sum + scanw[wv];
#pragma unroll
    for (int i = 0; i < 25; i++) {
        int c = cnt[kbase + i];
        cnt[kbase + i] = run;
        run += c;
    }
    __syncthreads();
    int base0 = bbase[b];
    {
        int node = nodeBase + t;
        if (t < BNODES && node < N_NODES) row_start[node] = base0 + cnt[t * NSPLIT];
    }
    __syncthreads();
    for (int s = grp; s < P1_BLOCKS; s += 4) {
        int n = pcnt[b * P1_BLOCKS + s];
        const int* seg = &stage[((long)b * P1_BLOCKS + s) * CAPB];
        for (int i = gt; i < n; i += 128) {
            int pk = seg[i];
            int pos = atomicAdd(&cnt[(pk & (BNODES - 1)) * NSPLIT + (pk >> (BSHIFT + SRC_SHIFT))], 1);
            esrc[base0 + pos] = pk >> BSHIFT;
        }
    }
}

// ---------------- cast x -> chunk-major fp16: xc[c][node][16] ----------------
__global__ void k_cast(const float* __restrict__ x, _Float16* __restrict__ xc) {
    int i = blockIdx.x * blockDim.x + threadIdx.x;  // 800000 threads
    int node = i >> 3, c = i & 7;
    const float* xp = &x[(long)node * F + c * 16];
    _Float16 h[16];
#pragma unroll
    for (int j = 0; j < 16; j++) h[j] = (_Float16)xp[j];
    _Float16* op = &xc[((long)c * N_NODES + node) * 16];
    *(f16x8*)op = *(f16x8*)&h[0];
    *(f16x8*)(op + 8) = *(f16x8*)&h[8];
}

// Wt[n][k] fp16 for both layers in one launch
__global__ void k_prepw(const float* __restrict__ Ws1, const float* __restrict__ Wn1,
                        const float* __restrict__ Ws2, const float* __restrict__ Wn2,
                        _Float16* __restrict__ Wt1, _Float16* __restrict__ Wt2) {
    int i = blockIdx.x * blockDim.x + threadIdx.x;
    int which = i >> 15;
    int j = i & 32767;
    int n = j >> 8;
    int k = j & 255;
    const float* Ws = which ? Ws2 : Ws1;
    const float* Wn = which ? Wn2 : Wn1;
    _Float16* Wt = which ? Wt2 : Wt1;
    float v = (k < 128) ? Ws[k * F + n] : Wn[(k - 128) * F + n];
    Wt[n * 256 + k] = (_Float16)v;
}

// ---------------- aggregation: chunk-plane (XCD-L2-pinned), 8 nodes per wave ----------------
// 25000 blocks (dispatch-rate safe). chunk = blockIdx&7 pins each 3.2 MB plane to one XCD.
// Per node: lane = (edge slot lane>>2, col4 lane&3); quad shares one esrc dword (HW
// broadcast), each lane gathers 8 B of the 32 B row; pk_f16 accumulate; shfl_xor reduce.
__global__ __launch_bounds__(256) void k_agg(const _Float16* __restrict__ xc,
                                             const int* __restrict__ row_start,
                                             const int* __restrict__ esrc,
                                             _Float16* __restrict__ outc) {
    int c = blockIdx.x & 7;
    int nb = blockIdx.x >> 3;                 // 0..3124
    int w = threadIdx.x >> 6;
    int lane = threadIdx.x & 63;
    int eidx = lane >> 2;                     // edge slot 0..15
    int col4 = lane & 3;                      // f16x4 within 32 B row
    const _Float16* plane = xc + (long)c * (N_NODES * 16);
    int node0 = nb * 32 + w * 8;              // 3125*32 == 100000 exact
#pragma unroll
    for (int n = 0; n < 8; n++) {
        int node = node0 + n;
        int beg = row_start[node], end = row_start[node + 1];
        int deg = end - beg;
        f16x2 a0 = (f16x2){(_Float16)0.f, (_Float16)0.f};
        f16x2 a1 = a0;
        for (int i = 0; i < deg; i += 16) {
            int idx = i + eidx;
            bool valid = idx < deg;
            // may read up to 15 ints past row end: masked to 0 below and esrc is
            // followed by live ws data, so the address stays in-bounds.
            int e = __builtin_nontemporal_load(&esrc[beg + idx]);
            e = valid ? e : 0;
            const f16x2* rp = (const f16x2*)&plane[(long)e * 16 + col4 * 4];  // 8 B fragment
            f16x2 v0 = rp[0];
            f16x2 v1 = rp[1];
            if (valid) {
                a0 += v0;
                a1 += v1;
            }
        }
        // reduce across the 16 edge slots (lanes with equal col4)
#pragma unroll
        for (int off = 4; off <= 32; off <<= 1) {
            int t0 = __shfl_xor(*(int*)&a0, off, 64);
            int t1 = __shfl_xor(*(int*)&a1, off, 64);
            a0 += *(f16x2*)&t0;
            a1 += *(f16x2*)&t1;
        }
        if (eidx == 0) {
            float invf = (deg > 0) ? 1.0f / (float)deg : 0.0f;
            _Float16 ih = (_Float16)invf;
            f16x2 iv = (f16x2){ih, ih};
            a0 *= iv;
            a1 *= iv;
            f16x4 r = (f16x4){a0.x, a0.y, a1.x, a1.y};
            __builtin_nontemporal_store(r, (f16x4*)&outc[((long)c * N_NODES + node) * 16 + col4 * 4]);
        }
    }
}

// ---------------- MFMA GEMM (A chunk-major, B staged in LDS fragment-order) ----------------
template <bool FINAL>
__global__ __launch_bounds__(256, 2) void k_gemm_mfma(
    const _Float16* __restrict__ Aself, const _Float16* __restrict__ Aneigh,
    const _Float16* __restrict__ Wt, const float* __restrict__ bias,
    _Float16* __restrict__ Hout, const float* __restrict__ Wf,
    const float* __restrict__ bf, float* __restrict__ Out) {
    const int M = N_NODES;
    __shared__ _Float16 Wl[4096 * 8];  // 64 KB
    int w = threadIdx.x >> 6;
    int lane = threadIdx.x & 63;
    int q = lane >> 4;
    int ln = lane & 15;
    int rBase = blockIdx.x * 128 + w * 32;

#pragma unroll
    for (int i = 0; i < 16; i++) {
        int s = threadIdx.x + i * 256;
        int L = s & 63, ct = (s >> 6) & 7, ks = s >> 9;
        int g = (ct * 16 + (L & 15)) * 256 + ks * 32 + (L >> 4) * 8;
        *(f16x8*)&Wl[s * 8] = *(const f16x8*)&Wt[g];
    }

    f32x4 acc[2][8];
#pragma unroll
    for (int rt = 0; rt < 2; rt++)
#pragma unroll
        for (int ct = 0; ct < 8; ct++) acc[rt][ct] = (f32x4){0.f, 0.f, 0.f, 0.f};

    __syncthreads();

    for (int ks = 0; ks < 8; ks++) {
        const _Float16* Abase = (ks < 4) ? Aself : Aneigh;
        int kk = (ks & 3) * 32 + q * 8;
        int chk = kk >> 4;
        int inner = kk & 15;
        f16x8 b[8];
#pragma unroll
        for (int ct = 0; ct < 8; ct++)
            b[ct] = *(const f16x8*)&Wl[((ks * 8 + ct) * 64 + lane) * 8];
#pragma unroll
        for (int rt = 0; rt < 2; rt++) {
            int row = rBase + rt * 16 + ln;
            f16x8 a = {};
            if (row < M) a = *(const f16x8*)&Abase[((long)chk * N_NODES + row) * 16 + inner];
#pragma unroll
            for (int ct = 0; ct < 8; ct++)
                acc[rt][ct] = __builtin_amdgcn_mfma_f32_16x16x32_f16(a, b[ct], acc[rt][ct], 0, 0, 0);
        }
    }

    float bv[8];
#pragma unroll
    for (int ct = 0; ct < 8; ct++) bv[ct] = bias[ct * 16 + ln];

    if (!FINAL) {
#pragma unroll
        for (int rt = 0; rt < 2; rt++) {
#pragma unroll
            for (int r = 0; r < 4; r++) {
                int row = rBase + rt * 16 + q * 4 + r;
                if (row < M) {
#pragma unroll
                    for (int ct = 0; ct < 8; ct++) {
                        float h = acc[rt][ct][r] + bv[ct];
                        h = h > 0.f ? h : 0.f;
                        Hout[((long)ct * N_NODES + row) * 16 + ln] = (_Float16)h;
                    }
                }
            }
        }
    } else {
        float wf0[8], wf1[8];
#pragma unroll
        for (int ct = 0; ct < 8; ct++) {
            int c = ct * 16 + ln;
            wf0[ct] = Wf[c * 2 + 0];
            wf1[ct] = Wf[c * 2 + 1];
        }
        float bf0 = bf[0], bf1 = bf[1];
#pragma unroll
        for (int rt = 0; rt < 2; rt++) {
#pragma unroll
            for (int r = 0; r < 4; r++) {
                int row = rBase + rt * 16 + q * 4 + r;
                float p0 = 0.f, p1 = 0.f;
#pragma unroll
                for (int ct = 0; ct < 8; ct++) {
                    float h = acc[rt][ct][r] + bv[ct];
                    h = h > 0.f ? h : 0.f;
                    p0 += h * wf0[ct];
                    p1 += h * wf1[ct];
                }
#pragma unroll
                for (int off = 1; off < 16; off <<= 1) {
                    p0 += __shfl_xor(p0, off, 64);
                    p1 += __shfl_xor(p1, off, 64);
                }
                if (ln == 0 && row < M) {
                    Out[(long)row * 2 + 0] = p0 + bf0;
                    Out[(long)row * 2 + 1] = p1 + bf1;
                }
            }
        }
    }
}

// ---------------- launch ----------------
extern "C" void kernel_launch(void* const* d_in, const int* in_sizes, int n_in,
                              void* d_out, int out_size, void* d_ws, size_t ws_size,
                              hipStream_t stream) {
    const float* x   = (const float*)d_in[0];
    const float* Ws1 = (const float*)d_in[1];
    const float* Wn1 = (const float*)d_in[2];
    const float* b1  = (const float*)d_in[3];
    const float* Ws2 = (const float*)d_in[4];
    const float* Wn2 = (const float*)d_in[5];
    const float* b2  = (const float*)d_in[6];
    const float* Wf  = (const float*)d_in[7];
    const float* bf  = (const float*)d_in[8];
    const int* src   = (const int*)d_in[9];
    const int* dst   = (const int*)d_in[10];
    float* out = (float*)d_out;

    char* ws = (char*)d_ws;
    int*      row_start = (int*)(ws + 0);               // 400,016
    int*      bbase     = (int*)(ws + 400016);          // 800
    int*      pcnt      = (int*)(ws + 400816);          // 100,352
    int*      stage     = (int*)(ws + 501184);          // 16,056,320
    int*      esrc      = (int*)(ws + 16557504);        // 6,400,000 (+64 B over-read slack into xh)
    _Float16* xh        = (_Float16*)(ws + 22957504);   // 25,600,000 (chunk-major)
    _Float16* hneigh    = (_Float16*)(ws + 48557504);   // 25,600,000 (chunk-major)
    _Float16* h1        = (_Float16*)(ws + 74157504);   // 25,600,000 (chunk-major)
    _Float16* Wt1       = (_Float16*)(ws + 99757504);   // 65,536
    _Float16* Wt2       = (_Float16*)(ws + 99823040);   // 65,536

    // CSR build (src-sorted rows, single-pass counting sort)
    k_part<<<P1_BLOCKS, P1_TPB, 0, stream>>>(src, dst, stage, pcnt);
    k_bucketsum<<<1, 256, 0, stream>>>(pcnt, bbase, row_start);
    k_build<<<NBUCK, P2_TPB, 0, stream>>>(stage, pcnt, bbase, row_start, esrc);

    // dtype prep
    k_cast<<<3125, 256, 0, stream>>>(x, xh);
    k_prepw<<<256, 256, 0, stream>>>(Ws1, Wn1, Ws2, Wn2, Wt1, Wt2);

    // layer 1
    k_agg<<<25000, 256, 0, stream>>>(xh, row_start, esrc, hneigh);
    k_gemm_mfma<false><<<(N_NODES + 127) / 128, 256, 0, stream>>>(
        xh, hneigh, Wt1, b1, h1, nullptr, nullptr, nullptr);
    // layer 2 + fused final projection
    k_agg<<<25000, 256, 0, stream>>>(h1, row_start, esrc, hneigh);
    k_gemm_mfma<true><<<(N_NODES + 127) / 128, 256, 0, stream>>>(
        h1, hneigh, Wt2, b2, nullptr, Wf, bf, out);
}